// Round 1
// baseline (453.154 us; speedup 1.0000x reference)
//
#include <hip/hip_runtime.h>
#include <stdint.h>

typedef __bf16 bf16_t;
typedef float f32x4 __attribute__((ext_vector_type(4)));
typedef __bf16 bf16x8 __attribute__((ext_vector_type(8)));

#define D_ 1024
#define M_ 8192

__device__ __forceinline__ f32x4 mfma16(bf16x8 a, bf16x8 b, f32x4 c) {
  return __builtin_amdgcn_mfma_f32_16x16x32_bf16(a, b, c, 0, 0, 0);
}

__device__ __forceinline__ void gl_lds16(const bf16_t* g, bf16_t* l) {
  __builtin_amdgcn_global_load_lds(
      (const __attribute__((address_space(1))) unsigned int*)g,
      (__attribute__((address_space(3))) unsigned int*)l, 16, 0, 0);
}

// ---------------- fp32 -> bf16 convert (8 elems/thread) ----------------
__global__ __launch_bounds__(256) void cvt_bf16(const float* __restrict__ in,
                                                bf16_t* __restrict__ out, int n8) {
  int i = blockIdx.x * 256 + threadIdx.x;
  if (i >= n8) return;
  const f32x4* p = (const f32x4*)(in + (size_t)i * 8);
  f32x4 a = p[0], b = p[1];
  bf16x8 o;
  o[0] = (bf16_t)a.x; o[1] = (bf16_t)a.y; o[2] = (bf16_t)a.z; o[3] = (bf16_t)a.w;
  o[4] = (bf16_t)b.x; o[5] = (bf16_t)b.y; o[6] = (bf16_t)b.z; o[7] = (bf16_t)b.w;
  *(bf16x8*)(out + (size_t)i * 8) = o;
}

// ---------------- shared 128x128x(K=1024) bf16 GEMM core (B stored N-major: C = A @ W^T) ----------------
__device__ __forceinline__ void gemm_core(const bf16_t* __restrict__ A,
                                          const bf16_t* __restrict__ W,
                                          int m0, int n0,
                                          bf16_t* As, bf16_t* Bs,
                                          f32x4 acc[4][4]) {
  const int t = threadIdx.x;
  const int l = t & 63, w = t >> 6;
  const int wr = w >> 1, wc = w & 1;
  const int lr = l & 15, lg = l >> 4;
  const int srow = t >> 2;          // 0..63
  const int scol = (t & 3) * 8;     // 0,8,16,24
  const bf16_t* gA0 = A + (size_t)(m0 + srow) * D_ + scol;
  const bf16_t* gA1 = A + (size_t)(m0 + 64 + srow) * D_ + scol;
  const bf16_t* gB0 = W + (size_t)(n0 + srow) * D_ + scol;
  const bf16_t* gB1 = W + (size_t)(n0 + 64 + srow) * D_ + scol;

  for (int k0 = 0; k0 < D_; k0 += 32) {
    gl_lds16(gA0 + k0, As + t * 8);
    gl_lds16(gA1 + k0, As + 2048 + t * 8);
    gl_lds16(gB0 + k0, Bs + t * 8);
    gl_lds16(gB1 + k0, Bs + 2048 + t * 8);
    __syncthreads();   // drains vmcnt -> staged data visible
    bf16x8 af[4], bfr[4];
#pragma unroll
    for (int i = 0; i < 4; ++i)
      af[i] = *(const bf16x8*)(As + (wr * 64 + i * 16 + lr) * 32 + lg * 8);
#pragma unroll
    for (int i = 0; i < 4; ++i)
      bfr[i] = *(const bf16x8*)(Bs + (wc * 64 + i * 16 + lr) * 32 + lg * 8);
#pragma unroll
    for (int mi = 0; mi < 4; ++mi)
#pragma unroll
      for (int ni = 0; ni < 4; ++ni)
        acc[mi][ni] = mfma16(af[mi], bfr[ni], acc[mi][ni]);
    __syncthreads();   // LDS reads done before next stage
  }
}

// ---------------- QKV GEMM: z selects (W, bias, out); out bf16 ----------------
__global__ __launch_bounds__(256) void gemm_qkv(
    const bf16_t* __restrict__ A,
    const bf16_t* __restrict__ Wq, const bf16_t* __restrict__ Wk, const bf16_t* __restrict__ Wv,
    const float* __restrict__ bq, const float* __restrict__ bk, const float* __restrict__ bv,
    bf16_t* __restrict__ Oq, bf16_t* __restrict__ Ok, bf16_t* __restrict__ Ov) {
  __shared__ bf16_t As[128 * 32], Bs[128 * 32];
  int z = blockIdx.z;
  const bf16_t* W = z == 0 ? Wq : (z == 1 ? Wk : Wv);
  const float* bias = z == 0 ? bq : (z == 1 ? bk : bv);
  bf16_t* O = z == 0 ? Oq : (z == 1 ? Ok : Ov);
  int m0 = blockIdx.y * 128, n0 = blockIdx.x * 128;
  f32x4 acc[4][4] = {};
  gemm_core(A, W, m0, n0, As, Bs, acc);
  int t = threadIdx.x, l = t & 63, w = t >> 6;
  int wr = w >> 1, wc = w & 1, lr = l & 15, lg = l >> 4;
#pragma unroll
  for (int mi = 0; mi < 4; ++mi) {
#pragma unroll
    for (int ni = 0; ni < 4; ++ni) {
      int col = n0 + wc * 64 + ni * 16 + lr;
      float bb = bias[col];
      int row = m0 + wr * 64 + mi * 16 + lg * 4;
      bf16_t* op = O + (size_t)row * D_ + col;
#pragma unroll
      for (int r = 0; r < 4; ++r)
        op[(size_t)r * D_] = (bf16_t)(acc[mi][ni][r] + bb);
    }
  }
}

// ---------------- proj GEMM: out fp32 = acc + bo + x (residual) ----------------
__global__ __launch_bounds__(256) void gemm_proj(
    const bf16_t* __restrict__ A, const bf16_t* __restrict__ W,
    const float* __restrict__ bias, const float* __restrict__ xres,
    float* __restrict__ O) {
  __shared__ bf16_t As[128 * 32], Bs[128 * 32];
  int m0 = blockIdx.y * 128, n0 = blockIdx.x * 128;
  f32x4 acc[4][4] = {};
  gemm_core(A, W, m0, n0, As, Bs, acc);
  int t = threadIdx.x, l = t & 63, w = t >> 6;
  int wr = w >> 1, wc = w & 1, lr = l & 15, lg = l >> 4;
#pragma unroll
  for (int mi = 0; mi < 4; ++mi) {
#pragma unroll
    for (int ni = 0; ni < 4; ++ni) {
      int col = n0 + wc * 64 + ni * 16 + lr;
      float bb = bias[col];
      int row = m0 + wr * 64 + mi * 16 + lg * 4;
#pragma unroll
      for (int r = 0; r < 4; ++r) {
        size_t idx = (size_t)(row + r) * D_ + col;
        O[idx] = acc[mi][ni][r] + bb + xres[idx];
      }
    }
  }
}

// ---------------- V transpose: [128][1024][64] -> [128][64][1024] ----------------
__global__ __launch_bounds__(256) void transpose_v(const bf16_t* __restrict__ V,
                                                   bf16_t* __restrict__ Vt) {
  int gid = blockIdx.x * 256 + threadIdx.x;  // 1,048,576 total
  int s8 = gid & 127;
  int dh = (gid >> 7) & 63;
  int bh = gid >> 13;
  const bf16_t* src = V + (size_t)bh * 65536 + (size_t)(s8 * 8) * 64 + dh;
  bf16x8 v;
#pragma unroll
  for (int j = 0; j < 8; ++j) v[j] = src[(size_t)j * 64];
  *(bf16x8*)(Vt + (size_t)bh * 65536 + (size_t)dh * 1024 + s8 * 8) = v;
}

// ---------------- fused attention per (bh, 32-row q tile) ----------------
// sS column swizzle: physical_c4 = logical_c4 ^ (row & 7)   (float4 units)
__global__ __launch_bounds__(512) void attn_kernel(
    const bf16_t* __restrict__ Q, const bf16_t* __restrict__ K,
    const bf16_t* __restrict__ Vt, float* __restrict__ alpha,
    bf16_t* __restrict__ ctx) {
  __shared__ float sS[32][1028];
  __shared__ float sL[32];
  int id = blockIdx.x;
  int bh = id & 127, qt = id >> 7;    // same-bh blocks land on same XCD (id step 128 ≡ 0 mod 8)
  int q0 = qt * 32;
  const bf16_t* Qb = Q + (size_t)bh * 65536;
  const bf16_t* Kb = K + (size_t)bh * 65536;
  const bf16_t* Vb = Vt + (size_t)bh * 65536;
  float* Ab = alpha + (size_t)bh * 1048576 + (size_t)q0 * 1024;

  int t = threadIdx.x, l = t & 63, w = t >> 6;
  int lr = l & 15, lg = l >> 4;

  // ---- Phase A: scores = 0.125 * Q @ K^T -> LDS ----
  bf16x8 qa[2][2];
#pragma unroll
  for (int mi = 0; mi < 2; ++mi)
#pragma unroll
    for (int kk = 0; kk < 2; ++kk)
      qa[mi][kk] = *(const bf16x8*)(Qb + (size_t)(q0 + mi * 16 + lr) * 64 + kk * 32 + lg * 8);

#pragma unroll 2
  for (int tt = 0; tt < 8; ++tt) {
    int n0 = w * 128 + tt * 16;
    bf16x8 kb0 = *(const bf16x8*)(Kb + (size_t)(n0 + lr) * 64 + lg * 8);
    bf16x8 kb1 = *(const bf16x8*)(Kb + (size_t)(n0 + lr) * 64 + 32 + lg * 8);
    f32x4 a0 = {0.f, 0.f, 0.f, 0.f};
    f32x4 a1 = {0.f, 0.f, 0.f, 0.f};
    a0 = mfma16(qa[0][0], kb0, a0);
    a0 = mfma16(qa[0][1], kb1, a0);
    a1 = mfma16(qa[1][0], kb0, a1);
    a1 = mfma16(qa[1][1], kb1, a1);
    int c4 = (n0 + lr) >> 2, cj = (n0 + lr) & 3;
#pragma unroll
    for (int r = 0; r < 4; ++r) {
      int row0 = lg * 4 + r;
      sS[row0][((c4 ^ (row0 & 7)) << 2) | cj] = a0[r] * 0.125f;
      int row1 = 16 + row0;
      sS[row1][((c4 ^ (row1 & 7)) << 2) | cj] = a1[r] * 0.125f;
    }
  }
  __syncthreads();

  // ---- Phase B: exp in place + row sums (no max-sub: |s| < ~3) ----
  {
    int row = t >> 4, seg = t & 15;
    float sum = 0.f;
#pragma unroll 4
    for (int i = 0; i < 16; ++i) {
      int c4 = i * 16 + seg;                 // seg varies fastest across lanes -> bank-spread
      int c4s = c4 ^ (row & 7);
      f32x4* p = (f32x4*)&sS[row][c4s << 2];
      f32x4 v = *p;
      v[0] = __expf(v[0]); v[1] = __expf(v[1]);
      v[2] = __expf(v[2]); v[3] = __expf(v[3]);
      *p = v;
      sum += v[0] + v[1] + v[2] + v[3];
    }
    sum += __shfl_xor(sum, 1);
    sum += __shfl_xor(sum, 2);
    sum += __shfl_xor(sum, 4);
    sum += __shfl_xor(sum, 8);
    if (seg == 0) sL[row] = sum;
  }
  __syncthreads();

  // ---- alpha = e / L, coalesced f32x4 stores ----
  {
    int rr0 = t >> 8, c4 = t & 255;
#pragma unroll 2
    for (int r2 = 0; r2 < 16; ++r2) {
      int row = r2 * 2 + rr0;
      float inv = 1.0f / sL[row];
      f32x4 v = *(const f32x4*)&sS[row][(c4 ^ (row & 7)) << 2];
      f32x4 o = v * inv;
      *(f32x4*)(Ab + (size_t)row * 1024 + c4 * 4) = o;
    }
  }

  // ---- Phase C: PV. wave tile 16q x 16dh; ctx = (e @ V) / L ----
  {
    int wm = w >> 2, wn = w & 3;
    int row = wm * 16 + lr;
    f32x4 acc = {0.f, 0.f, 0.f, 0.f};
    const bf16_t* vp = Vb + (size_t)(wn * 16 + lr) * 1024 + lg * 8;
#pragma unroll 4
    for (int n0 = 0; n0 < 1024; n0 += 32) {
      int c4 = (n0 >> 2) + (lg << 1);
      f32x4 e0 = *(const f32x4*)&sS[row][((c4) ^ (row & 7)) << 2];
      f32x4 e1 = *(const f32x4*)&sS[row][((c4 + 1) ^ (row & 7)) << 2];
      bf16x8 ea;
      ea[0] = (bf16_t)e0[0]; ea[1] = (bf16_t)e0[1]; ea[2] = (bf16_t)e0[2]; ea[3] = (bf16_t)e0[3];
      ea[4] = (bf16_t)e1[0]; ea[5] = (bf16_t)e1[1]; ea[6] = (bf16_t)e1[2]; ea[7] = (bf16_t)e1[3];
      bf16x8 vb = *(const bf16x8*)(vp + n0);
      acc = mfma16(ea, vb, acc);
    }
    bf16_t* cp = ctx + (size_t)bh * 65536 + (size_t)(q0 + wm * 16 + lg * 4) * 64 + wn * 16 + lr;
#pragma unroll
    for (int r = 0; r < 4; ++r)
      cp[(size_t)r * 64] = (bf16_t)(acc[r] / sL[wm * 16 + lg * 4 + r]);
  }
}

// ---------------- LayerNorm in place on d_out rows ----------------
__global__ __launch_bounds__(256) void ln_kernel(float* __restrict__ io,
                                                 const float* __restrict__ gamma,
                                                 const float* __restrict__ beta) {
  int row = blockIdx.x;
  int t = threadIdx.x;
  float* p = io + (size_t)row * 1024;
  f32x4 v = *(const f32x4*)(p + t * 4);
  float s = v[0] + v[1] + v[2] + v[3];
  float s2 = v[0] * v[0] + v[1] * v[1] + v[2] * v[2] + v[3] * v[3];
#pragma unroll
  for (int off = 1; off <= 32; off <<= 1) {
    s += __shfl_xor(s, off);
    s2 += __shfl_xor(s2, off);
  }
  __shared__ float ps[4], ps2[4];
  int w = t >> 6, l = t & 63;
  if (l == 0) { ps[w] = s; ps2[w] = s2; }
  __syncthreads();
  float S = ps[0] + ps[1] + ps[2] + ps[3];
  float S2 = ps2[0] + ps2[1] + ps2[2] + ps2[3];
  float mu = S * (1.f / 1024.f);
  float var = S2 * (1.f / 1024.f) - mu * mu;
  float rs = rsqrtf(var + 1e-5f);
  f32x4 g = *(const f32x4*)(gamma + t * 4);
  f32x4 b = *(const f32x4*)(beta + t * 4);
  f32x4 o;
  o[0] = (v[0] - mu) * rs * g[0] + b[0];
  o[1] = (v[1] - mu) * rs * g[1] + b[1];
  o[2] = (v[2] - mu) * rs * g[2] + b[2];
  o[3] = (v[3] - mu) * rs * g[3] + b[3];
  *(f32x4*)(p + t * 4) = o;
}

extern "C" void kernel_launch(void* const* d_in, const int* in_sizes, int n_in,
                              void* d_out, int out_size, void* d_ws, size_t ws_size,
                              hipStream_t stream) {
  const float* x = (const float*)d_in[0];
  const float* Wq = (const float*)d_in[1];
  const float* bq = (const float*)d_in[2];
  const float* Wk = (const float*)d_in[3];
  const float* bk = (const float*)d_in[4];
  const float* Wv = (const float*)d_in[5];
  const float* bv = (const float*)d_in[6];
  const float* Wo = (const float*)d_in[7];
  const float* bo = (const float*)d_in[8];
  const float* gamma = (const float*)d_in[9];
  const float* beta = (const float*)d_in[10];

  char* ws = (char*)d_ws;
  size_t off = 0;
  bf16_t* xb = (bf16_t*)(ws + off);  off += (size_t)M_ * D_ * 2;       // 16.78 MB
  bf16_t* Wqb = (bf16_t*)(ws + off); off += (size_t)D_ * D_ * 2;       // 2.1 MB
  bf16_t* Wkb = (bf16_t*)(ws + off); off += (size_t)D_ * D_ * 2;
  bf16_t* Wvb = (bf16_t*)(ws + off); off += (size_t)D_ * D_ * 2;
  bf16_t* Wob = (bf16_t*)(ws + off); off += (size_t)D_ * D_ * 2;
  bf16_t* Qb = (bf16_t*)(ws + off);  off += (size_t)M_ * D_ * 2;
  bf16_t* Kb = (bf16_t*)(ws + off);  off += (size_t)M_ * D_ * 2;
  bf16_t* Vb = (bf16_t*)(ws + off);  off += (size_t)M_ * D_ * 2;
  bf16_t* Vtb = (bf16_t*)(ws + off); off += (size_t)M_ * D_ * 2;
  bf16_t* ctxb = (bf16_t*)(ws + off); off += (size_t)M_ * D_ * 2;      // total ~109 MB

  float* out0 = (float*)d_out;
  float* alpha = out0 + (size_t)M_ * D_;

  cvt_bf16<<<4096, 256, 0, stream>>>(x, xb, 1048576);
  cvt_bf16<<<512, 256, 0, stream>>>(Wq, Wqb, 131072);
  cvt_bf16<<<512, 256, 0, stream>>>(Wk, Wkb, 131072);
  cvt_bf16<<<512, 256, 0, stream>>>(Wv, Wvb, 131072);
  cvt_bf16<<<512, 256, 0, stream>>>(Wo, Wob, 131072);

  gemm_qkv<<<dim3(8, 64, 3), 256, 0, stream>>>(xb, Wqb, Wkb, Wvb, bq, bk, bv, Qb, Kb, Vb);
  transpose_v<<<4096, 256, 0, stream>>>(Vb, Vtb);
  attn_kernel<<<4096, 512, 0, stream>>>(Qb, Kb, Vtb, alpha, ctxb);
  gemm_proj<<<dim3(8, 64), 256, 0, stream>>>(ctxb, Wob, bo, x, out0);
  ln_kernel<<<8192, 256, 0, stream>>>(out0, gamma, beta);
}